// Round 1
// baseline (309.576 us; speedup 1.0000x reference)
//
#include <hip/hip_runtime.h>
#include <hip/hip_bf16.h>
#include <stdint.h>

// Problem constants
#define M_B   1536      // 64*24 batch rows
#define N_L   500       // links
#define N_LP  512       // padded links (K of GEMM1, N of GEMM2)
#define N_P   20000     // paths
#define N_PP  20096     // padded paths (N of GEMM1 = 157*128, K of GEMM2)
#define N_G   4000      // OD groups
#define SPLITK 16
#define KCHUNK2 1280    // split-K chunk for GEMM2 (last chunk = 896, both %32==0)

// Workspace layout (bytes). Total ~228 MB. partial aliases vp (vp dead after softmax).
#define OFF_A1   ((size_t)0)                    // bf16 [1536][512]      1,572,864
#define OFF_D1   ((size_t)1572864)              // bf16 [512][20096]    20,578,304
#define OFF_DT   ((size_t)22151168)             // bf16 [20096][512]    20,578,304
#define OFF_VP   ((size_t)42729472)             // f32  [1536][20096]  123,469,824
#define OFF_PART OFF_VP                         // f32  [16][1536][512] 50,331,648 (aliases vp)
#define OFF_F    ((size_t)166199296)            // bf16 [1536][20096]   61,734,912
#define OFF_BND  ((size_t)227934208)            // int  [4001]

typedef __bf16 bf16x8 __attribute__((ext_vector_type(8)));
typedef float  f32x4  __attribute__((ext_vector_type(4)));

__device__ __forceinline__ void gload16(const void* g, void* l) {
  __builtin_amdgcn_global_load_lds(
      (const __attribute__((address_space(1))) void*)g,
      (__attribute__((address_space(3))) void*)l, 16, 0, 0);
}

// ---- prep: v_links -> bf16 A1 [1536][512], zero-padded ----
__global__ __launch_bounds__(256) void prep_a1(const float* __restrict__ X,
                                               const float* __restrict__ theta,
                                               const float* __restrict__ theta_links,
                                               __bf16* __restrict__ A1) {
  int idx = blockIdx.x * 256 + threadIdx.x;           // over 1536*512
  if (idx >= M_B * N_LP) return;
  int b = idx >> 9, l = idx & (N_LP - 1);
  float v = 0.f;
  if (l < N_L) {
    const float* x = X + ((size_t)b * N_L + l) * 5;
#pragma unroll
    for (int f = 0; f < 5; ++f) v += x[f] * fminf(theta[f], 0.f);
    v += theta_links[l];
  }
  A1[idx] = (__bf16)v;
}

// ---- prep: D -> bf16 D1 [512][20096], zero-padded (GEMM2's Bt) ----
__global__ __launch_bounds__(256) void prep_d1(const float* __restrict__ D,
                                               __bf16* __restrict__ D1) {
  int idx = blockIdx.x * 256 + threadIdx.x;           // over 512*20096
  if (idx >= N_LP * N_PP) return;
  int l = idx / N_PP, p = idx - l * N_PP;
  float v = (l < N_L && p < N_P) ? D[(size_t)l * N_P + p] : 0.f;
  D1[idx] = (__bf16)v;
}

// ---- prep: D -> bf16 Dt [20096][512] transposed, zero-padded (GEMM1's Bt) ----
__global__ __launch_bounds__(256) void prep_dt(const float* __restrict__ D,
                                               __bf16* __restrict__ Dt) {
  __shared__ float t[32][33];
  int pb = blockIdx.x * 32;   // path block
  int lb = blockIdx.y * 32;   // link block
  for (int i = threadIdx.y; i < 32; i += 8) {
    int l = lb + i, p = pb + threadIdx.x;
    t[i][threadIdx.x] = (l < N_L && p < N_P) ? D[(size_t)l * N_P + p] : 0.f;
  }
  __syncthreads();
  for (int i = threadIdx.y; i < 32; i += 8) {
    int p = pb + i, l = lb + threadIdx.x;
    Dt[(size_t)p * N_LP + l] = (__bf16)t[threadIdx.x][i];
  }
}

// ---- segment bounds: bounds[g] = first path index with seg >= g, g in [0,4000] ----
__global__ __launch_bounds__(256) void seg_bounds(const int* __restrict__ seg,
                                                  int* __restrict__ bounds) {
  int g = blockIdx.x * 256 + threadIdx.x;
  if (g > N_G) return;
  int lo = 0, hi = N_P;
  while (lo < hi) { int mid = (lo + hi) >> 1; if (seg[mid] < g) lo = mid + 1; else hi = mid; }
  bounds[g] = lo;
}

// ---- GEMM (both A and Bt row-major over K): C[m][n] = sum_k A[m][k]*Bt[n][k] ----
// 128x128 tile, 4 waves (2x2), 4x4 16x16x32 frags per wave, BK=32, global_load_lds staging.
__global__ __launch_bounds__(256) void gemm_bt(const __bf16* __restrict__ A,
                                               const __bf16* __restrict__ Bt,
                                               float* __restrict__ C,
                                               int lda, int ldb, int ldc,
                                               int K, int kchunk, size_t zstride) {
  __shared__ __bf16 lsA[128 * 32];
  __shared__ __bf16 lsB[128 * 32];
  const int tid = threadIdx.x;
  const int lane = tid & 63;
  const int wv = tid >> 6;
  const int wr = wv >> 1, wc = wv & 1;
  const int m0 = blockIdx.y * 128;
  const int n0 = blockIdx.x * 128;
  const int kb = blockIdx.z * kchunk;
  const int klen = min(kchunk, K - kb);

  // staging: per wave, instr j covers rows j*64 + wv*16 .. +15 of the tile
  const int srow = wv * 16 + (lane >> 2);
  const int scol = (lane & 3) * 8;
  const __bf16* gA = A + (size_t)(m0 + srow) * lda + kb + scol;
  const __bf16* gB = Bt + (size_t)(n0 + srow) * ldb + kb + scol;
  __bf16* lA0 = &lsA[(wv * 16) * 32];
  __bf16* lA1 = &lsA[(64 + wv * 16) * 32];
  __bf16* lB0 = &lsB[(wv * 16) * 32];
  __bf16* lB1 = &lsB[(64 + wv * 16) * 32];

  f32x4 acc[4][4] = {};
  const int fra = (wr * 64 + (lane & 15)) * 32 + 8 * (lane >> 4);
  const int frb = (wc * 64 + (lane & 15)) * 32 + 8 * (lane >> 4);

  for (int kk = 0; kk < klen; kk += 32) {
    gload16(gA + kk, lA0);
    gload16(gA + (size_t)64 * lda + kk, lA1);
    gload16(gB + kk, lB0);
    gload16(gB + (size_t)64 * ldb + kk, lB1);
    __syncthreads();
    bf16x8 av[4], bv[4];
#pragma unroll
    for (int r = 0; r < 4; ++r) av[r] = *(const bf16x8*)&lsA[fra + r * 16 * 32];
#pragma unroll
    for (int c = 0; c < 4; ++c) bv[c] = *(const bf16x8*)&lsB[frb + c * 16 * 32];
#pragma unroll
    for (int r = 0; r < 4; ++r)
#pragma unroll
      for (int c = 0; c < 4; ++c)
        acc[r][c] = __builtin_amdgcn_mfma_f32_16x16x32_bf16(av[r], bv[c], acc[r][c], 0, 0, 0);
    __syncthreads();
  }

  float* Cz = C + (size_t)blockIdx.z * zstride;
  const int erow = m0 + wr * 64 + (lane >> 4) * 4;
  const int ecol = n0 + wc * 64 + (lane & 15);
#pragma unroll
  for (int r = 0; r < 4; ++r)
#pragma unroll
    for (int c = 0; c < 4; ++c) {
      float* p = Cz + (size_t)(erow + r * 16) * ldc + (ecol + c * 16);
#pragma unroll
      for (int j = 0; j < 4; ++j) p[(size_t)j * ldc] = acc[r][c][j];
    }
}

// ---- grouped softmax over contiguous segments + scale by q -> f bf16 ----
__global__ __launch_bounds__(256) void seg_softmax(const float* __restrict__ vp,
                                                   const int* __restrict__ bounds,
                                                   const float* __restrict__ q_sqrt,
                                                   __bf16* __restrict__ f) {
  int b = blockIdx.x;
  const float* row = vp + (size_t)b * N_PP;
  __bf16* frow = f + (size_t)b * N_PP;
  for (int g = threadIdx.x; g < N_G; g += 256) {
    int s = bounds[g], e = bounds[g + 1];
    if (s >= e) continue;
    float m = -3.4e38f;
    for (int p = s; p < e; ++p) m = fmaxf(m, row[p]);
    float den = 0.f;
    for (int p = s; p < e; ++p) den += __expf(row[p] - m);
    float qs = q_sqrt[g];
    float sc = qs * qs / den;
    for (int p = s; p < e; ++p) frow[p] = (__bf16)(__expf(row[p] - m) * sc);
  }
  // zero padded tail so GEMM2's K-padding contributes nothing
  for (int p = N_P + threadIdx.x; p < N_PP; p += 256) frow[p] = (__bf16)0.f;
}

// ---- reduce split-K partials -> out (only l < 500) ----
__global__ __launch_bounds__(256) void reduce_out(const float* __restrict__ part,
                                                  float* __restrict__ out) {
  int idx = blockIdx.x * 256 + threadIdx.x;   // over 1536*500
  if (idx >= M_B * N_L) return;
  int b = idx / N_L, l = idx - b * N_L;
  float s = 0.f;
#pragma unroll
  for (int z = 0; z < SPLITK; ++z)
    s += part[(size_t)z * M_B * N_LP + (size_t)b * N_LP + l];
  out[idx] = s;
}

extern "C" void kernel_launch(void* const* d_in, const int* in_sizes, int n_in,
                              void* d_out, int out_size, void* d_ws, size_t ws_size,
                              hipStream_t stream) {
  const float* X           = (const float*)d_in[0];
  const float* theta       = (const float*)d_in[1];
  const float* theta_links = (const float*)d_in[2];
  const float* q_sqrt      = (const float*)d_in[3];
  const float* D           = (const float*)d_in[4];
  const int*   seg         = (const int*)d_in[5];
  float* out = (float*)d_out;

  char* ws = (char*)d_ws;
  __bf16* A1   = (__bf16*)(ws + OFF_A1);
  __bf16* D1   = (__bf16*)(ws + OFF_D1);
  __bf16* Dt   = (__bf16*)(ws + OFF_DT);
  float*  vp   = (float*)(ws + OFF_VP);
  float*  part = (float*)(ws + OFF_PART);
  __bf16* fbuf = (__bf16*)(ws + OFF_F);
  int*    bnd  = (int*)(ws + OFF_BND);

  prep_a1<<<(M_B * N_LP) / 256, 256, 0, stream>>>(X, theta, theta_links, A1);
  prep_d1<<<(N_LP * N_PP) / 256, 256, 0, stream>>>(D, D1);
  prep_dt<<<dim3(N_PP / 32, N_LP / 32), dim3(32, 8), 0, stream>>>(D, Dt);
  seg_bounds<<<16, 256, 0, stream>>>(seg, bnd);

  // GEMM1: vp[b][p] = sum_l A1[b][l] * Dt[p][l]
  gemm_bt<<<dim3(N_PP / 128, M_B / 128, 1), 256, 0, stream>>>(
      A1, Dt, vp, N_LP, N_LP, N_PP, N_LP, N_LP, (size_t)0);

  seg_softmax<<<M_B, 256, 0, stream>>>(vp, bnd, q_sqrt, fbuf);

  // GEMM2 (split-K): part[z][b][l] = sum_{k in chunk z} f[b][k] * D1[l][k]
  gemm_bt<<<dim3(N_LP / 128, M_B / 128, SPLITK), 256, 0, stream>>>(
      fbuf, D1, part, N_PP, N_PP, N_LP, N_PP, KCHUNK2, (size_t)(M_B * N_LP));

  reduce_out<<<(M_B * N_L + 255) / 256, 256, 0, stream>>>(part, out);
}

// Round 2
// 300.844 us; speedup vs baseline: 1.0290x; 1.0290x over previous
//
#include <hip/hip_runtime.h>
#include <hip/hip_bf16.h>
#include <stdint.h>

// Problem constants
#define M_B   1536      // 64*24 batch rows
#define N_L   500       // links
#define N_LP  512       // padded links (K of GEMM1, N of GEMM2)
#define N_P   20000     // paths
#define N_PP  20096     // padded paths (N of GEMM1 = 157*128, K of GEMM2)
#define N_G   4000      // OD groups
#define SPLITK 16
#define KCHUNK2 1280    // split-K chunk for GEMM2 (last chunk = 896, both %32==0)
#define SM_CAP 16000    // LDS floats per softmax block (half-row ~10000, margin ~6000)

// Workspace layout (bytes). Total ~228 MB. partial aliases vp (vp dead after softmax).
#define OFF_A1   ((size_t)0)                    // bf16 [1536][512]      1,572,864
#define OFF_D1   ((size_t)1572864)              // bf16 [512][20096]    20,578,304
#define OFF_DT   ((size_t)22151168)             // bf16 [20096][512]    20,578,304
#define OFF_VP   ((size_t)42729472)             // f32  [1536][20096]  123,469,824
#define OFF_PART OFF_VP                         // f32  [16][1536][512] 50,331,648 (aliases vp)
#define OFF_F    ((size_t)166199296)            // bf16 [1536][20096]   61,734,912
#define OFF_BND  ((size_t)227934208)            // int  [4001]

typedef __bf16 bf16x8 __attribute__((ext_vector_type(8)));
typedef __bf16 bf16x4 __attribute__((ext_vector_type(4)));
typedef float  f32x4  __attribute__((ext_vector_type(4)));

__device__ __forceinline__ void gload16(const void* g, void* l) {
  __builtin_amdgcn_global_load_lds(
      (const __attribute__((address_space(1))) void*)g,
      (__attribute__((address_space(3))) void*)l, 16, 0, 0);
}

// ---- prep: v_links -> bf16 A1 [1536][512], zero-padded ----
__global__ __launch_bounds__(256) void prep_a1(const float* __restrict__ X,
                                               const float* __restrict__ theta,
                                               const float* __restrict__ theta_links,
                                               __bf16* __restrict__ A1) {
  int idx = blockIdx.x * 256 + threadIdx.x;           // over 1536*512
  if (idx >= M_B * N_LP) return;
  int b = idx >> 9, l = idx & (N_LP - 1);
  float v = 0.f;
  if (l < N_L) {
    const float* x = X + ((size_t)b * N_L + l) * 5;
#pragma unroll
    for (int f = 0; f < 5; ++f) v += x[f] * fminf(theta[f], 0.f);
    v += theta_links[l];
  }
  A1[idx] = (__bf16)v;
}

// ---- prep: D -> bf16 D1 [512][20096], zero-padded (GEMM2's Bt), float4 in / bf16x4 out ----
__global__ __launch_bounds__(256) void prep_d1(const float* __restrict__ D,
                                               __bf16* __restrict__ D1) {
  int p4 = blockIdx.x * 256 + threadIdx.x;            // over N_PP/4 = 5024
  int l = blockIdx.y;
  if (p4 >= N_PP / 4) return;
  int p = p4 * 4;
  bf16x4 o;
  if (l < N_L && p + 3 < N_P) {
    float4 v = *(const float4*)&D[(size_t)l * N_P + p];
    o[0] = (__bf16)v.x; o[1] = (__bf16)v.y; o[2] = (__bf16)v.z; o[3] = (__bf16)v.w;
  } else {
#pragma unroll
    for (int j = 0; j < 4; ++j)
      o[j] = (__bf16)((l < N_L && p + j < N_P) ? D[(size_t)l * N_P + p + j] : 0.f);
  }
  *(bf16x4*)&D1[(size_t)l * N_PP + p] = o;
}

// ---- prep: D -> bf16 Dt [20096][512] transposed, zero-padded (GEMM1's Bt) ----
__global__ __launch_bounds__(256) void prep_dt(const float* __restrict__ D,
                                               __bf16* __restrict__ Dt) {
  __shared__ float t[32][33];
  int pb = blockIdx.x * 32;   // path block
  int lb = blockIdx.y * 32;   // link block
  for (int i = threadIdx.y; i < 32; i += 8) {
    int l = lb + i, p = pb + threadIdx.x;
    t[i][threadIdx.x] = (l < N_L && p < N_P) ? D[(size_t)l * N_P + p] : 0.f;
  }
  __syncthreads();
  for (int i = threadIdx.y; i < 32; i += 8) {
    int p = pb + i, l = lb + threadIdx.x;
    Dt[(size_t)p * N_LP + l] = (__bf16)t[threadIdx.x][i];
  }
}

// ---- segment bounds: bounds[g] = first path index with seg >= g, g in [0,4000] ----
__global__ __launch_bounds__(256) void seg_bounds(const int* __restrict__ seg,
                                                  int* __restrict__ bounds) {
  int g = blockIdx.x * 256 + threadIdx.x;
  if (g > N_G) return;
  int lo = 0, hi = N_P;
  while (lo < hi) { int mid = (lo + hi) >> 1; if (seg[mid] < g) lo = mid + 1; else hi = mid; }
  bounds[g] = lo;
}

// ---- GEMM (both A and Bt row-major over K): C[m][n] = sum_k A[m][k]*Bt[n][k] ----
__global__ __launch_bounds__(256) void gemm_bt(const __bf16* __restrict__ A,
                                               const __bf16* __restrict__ Bt,
                                               float* __restrict__ C,
                                               int lda, int ldb, int ldc,
                                               int K, int kchunk, size_t zstride) {
  __shared__ __bf16 lsA[128 * 32];
  __shared__ __bf16 lsB[128 * 32];
  const int tid = threadIdx.x;
  const int lane = tid & 63;
  const int wv = tid >> 6;
  const int wr = wv >> 1, wc = wv & 1;
  const int m0 = blockIdx.y * 128;
  const int n0 = blockIdx.x * 128;
  const int kb = blockIdx.z * kchunk;
  const int klen = min(kchunk, K - kb);

  const int srow = wv * 16 + (lane >> 2);
  const int scol = (lane & 3) * 8;
  const __bf16* gA = A + (size_t)(m0 + srow) * lda + kb + scol;
  const __bf16* gB = Bt + (size_t)(n0 + srow) * ldb + kb + scol;
  __bf16* lA0 = &lsA[(wv * 16) * 32];
  __bf16* lA1 = &lsA[(64 + wv * 16) * 32];
  __bf16* lB0 = &lsB[(wv * 16) * 32];
  __bf16* lB1 = &lsB[(64 + wv * 16) * 32];

  f32x4 acc[4][4] = {};
  const int fra = (wr * 64 + (lane & 15)) * 32 + 8 * (lane >> 4);
  const int frb = (wc * 64 + (lane & 15)) * 32 + 8 * (lane >> 4);

  for (int kk = 0; kk < klen; kk += 32) {
    gload16(gA + kk, lA0);
    gload16(gA + (size_t)64 * lda + kk, lA1);
    gload16(gB + kk, lB0);
    gload16(gB + (size_t)64 * ldb + kk, lB1);
    __syncthreads();
    bf16x8 av[4], bv[4];
#pragma unroll
    for (int r = 0; r < 4; ++r) av[r] = *(const bf16x8*)&lsA[fra + r * 16 * 32];
#pragma unroll
    for (int c = 0; c < 4; ++c) bv[c] = *(const bf16x8*)&lsB[frb + c * 16 * 32];
#pragma unroll
    for (int r = 0; r < 4; ++r)
#pragma unroll
      for (int c = 0; c < 4; ++c)
        acc[r][c] = __builtin_amdgcn_mfma_f32_16x16x32_bf16(av[r], bv[c], acc[r][c], 0, 0, 0);
    __syncthreads();
  }

  float* Cz = C + (size_t)blockIdx.z * zstride;
  const int erow = m0 + wr * 64 + (lane >> 4) * 4;
  const int ecol = n0 + wc * 64 + (lane & 15);
#pragma unroll
  for (int r = 0; r < 4; ++r)
#pragma unroll
    for (int c = 0; c < 4; ++c) {
      float* p = Cz + (size_t)(erow + r * 16) * ldc + (ecol + c * 16);
#pragma unroll
      for (int j = 0; j < 4; ++j) p[(size_t)j * ldc] = acc[r][c][j];
    }
}

// ---- grouped softmax, LDS-staged half-rows. blockIdx.x = row b, blockIdx.y = half ----
// Half h covers groups [h*2000, (h+1)*2000) and paths [bounds[g0], bounds[g1)).
// Halves partition [0, N_P); each group handled entirely by one thread (in-place LDS).
__global__ __launch_bounds__(256) void seg_softmax(const float* __restrict__ vp,
                                                   const int* __restrict__ bounds,
                                                   const float* __restrict__ q_sqrt,
                                                   __bf16* __restrict__ f) {
  __shared__ float sr[SM_CAP];
  const int b = blockIdx.x;
  const int half = blockIdx.y;
  const int g0 = half * (N_G / 2), g1 = g0 + N_G / 2;
  const int s0 = bounds[g0];
  const int e0 = (half == 1) ? N_P : bounds[g1];
  const int s0a = s0 & ~3;
  const int e0a = (e0 + 3) & ~3;
  const float* row = vp + (size_t)b * N_PP;

  // coalesced float4 load of [s0a, e0a)
  for (int i = s0a / 4 + threadIdx.x; i * 4 < e0a; i += 256)
    *(f32x4*)&sr[i * 4 - s0a] = *(const f32x4*)&row[i * 4];
  __syncthreads();

#define LR(p) sr[(p) - s0a]
  for (int g = g0 + threadIdx.x; g < g1; g += 256) {
    int s = bounds[g], e = bounds[g + 1];
    if (s >= e) continue;
    float m = -3.4e38f;
    for (int p = s; p < e; ++p) m = fmaxf(m, LR(p));
    float den = 0.f;
    for (int p = s; p < e; ++p) { float t = __expf(LR(p) - m); den += t; LR(p) = t; }
    float qs = q_sqrt[g];
    float sc = qs * qs / den;
    for (int p = s; p < e; ++p) LR(p) *= sc;
  }
  __syncthreads();

  __bf16* frow = f + (size_t)b * N_PP;
  // scalar head to 4-alignment
  const int s0w = (s0 + 3) & ~3;
  for (int p = s0 + threadIdx.x; p < min(s0w, e0); p += 256) frow[p] = (__bf16)LR(p);
  // vectorized middle
  const int e0w = e0 & ~3;
  for (int i = s0w / 4 + threadIdx.x; i * 4 < e0w; i += 256) {
    f32x4 v = *(const f32x4*)&LR(i * 4);
    bf16x4 o; o[0] = (__bf16)v[0]; o[1] = (__bf16)v[1]; o[2] = (__bf16)v[2]; o[3] = (__bf16)v[3];
    *(bf16x4*)&frow[i * 4] = o;
  }
  // scalar tail
  for (int p = max(e0w, s0w) + threadIdx.x; p < e0; p += 256) frow[p] = (__bf16)LR(p);
  // zero padded tail so GEMM2's K-padding contributes nothing
  if (half == 1)
    for (int p = N_P + threadIdx.x; p < N_PP; p += 256) frow[p] = (__bf16)0.f;
#undef LR
}

// ---- reduce split-K partials -> out (only l < 500) ----
__global__ __launch_bounds__(256) void reduce_out(const float* __restrict__ part,
                                                  float* __restrict__ out) {
  int idx = blockIdx.x * 256 + threadIdx.x;   // over 1536*500
  if (idx >= M_B * N_L) return;
  int b = idx / N_L, l = idx - b * N_L;
  float s = 0.f;
#pragma unroll
  for (int z = 0; z < SPLITK; ++z)
    s += part[(size_t)z * M_B * N_LP + (size_t)b * N_LP + l];
  out[idx] = s;
}

extern "C" void kernel_launch(void* const* d_in, const int* in_sizes, int n_in,
                              void* d_out, int out_size, void* d_ws, size_t ws_size,
                              hipStream_t stream) {
  const float* X           = (const float*)d_in[0];
  const float* theta       = (const float*)d_in[1];
  const float* theta_links = (const float*)d_in[2];
  const float* q_sqrt      = (const float*)d_in[3];
  const float* D           = (const float*)d_in[4];
  const int*   seg         = (const int*)d_in[5];
  float* out = (float*)d_out;

  char* ws = (char*)d_ws;
  __bf16* A1   = (__bf16*)(ws + OFF_A1);
  __bf16* D1   = (__bf16*)(ws + OFF_D1);
  __bf16* Dt   = (__bf16*)(ws + OFF_DT);
  float*  vp   = (float*)(ws + OFF_VP);
  float*  part = (float*)(ws + OFF_PART);
  __bf16* fbuf = (__bf16*)(ws + OFF_F);
  int*    bnd  = (int*)(ws + OFF_BND);

  prep_a1<<<(M_B * N_LP) / 256, 256, 0, stream>>>(X, theta, theta_links, A1);
  prep_d1<<<dim3((N_PP / 4 + 255) / 256, N_LP), 256, 0, stream>>>(D, D1);
  prep_dt<<<dim3(N_PP / 32, N_LP / 32), dim3(32, 8), 0, stream>>>(D, Dt);
  seg_bounds<<<16, 256, 0, stream>>>(seg, bnd);

  // GEMM1: vp[b][p] = sum_l A1[b][l] * Dt[p][l]
  gemm_bt<<<dim3(N_PP / 128, M_B / 128, 1), 256, 0, stream>>>(
      A1, Dt, vp, N_LP, N_LP, N_PP, N_LP, N_LP, (size_t)0);

  seg_softmax<<<dim3(M_B, 2), 256, 0, stream>>>(vp, bnd, q_sqrt, fbuf);

  // GEMM2 (split-K): part[z][b][l] = sum_{k in chunk z} f[b][k] * D1[l][k]
  gemm_bt<<<dim3(N_LP / 128, M_B / 128, SPLITK), 256, 0, stream>>>(
      fbuf, D1, part, N_PP, N_PP, N_LP, N_PP, KCHUNK2, (size_t)(M_B * N_LP));

  reduce_out<<<(M_B * N_L + 255) / 256, 256, 0, stream>>>(part, out);
}